// Round 3
// baseline (3362.495 us; speedup 1.0000x reference)
//
#include <hip/hip_runtime.h>
#include <hip/hip_bf16.h>
#include <math.h>

#define B_      4
#define L_      2048
#define DMODEL  1024
#define DINNER  2048
#define DSTATE  128
#define NHEADS  32
#define HEADDIM 64
#define DINPROJ 4384   // 2*DINNER + 2*DSTATE + NHEADS
#define CONVCH  2304   // DINNER + 2*DSTATE
#define NTOK    (B_*L_)

__device__ __forceinline__ float silu_f(float v) {
  return v / (1.0f + __expf(-v));
}

// ---------------- RMSNorm row scale (fused into GEMM1 A-load) ----------------
__global__ __launch_bounds__(256) void rms_scale_kernel(const float* __restrict__ x,
                                                        float* __restrict__ sc) {
  int row = blockIdx.x;
  const float* xr = x + (size_t)row * DMODEL;
  int tid = threadIdx.x;
  float4 v = *(const float4*)&xr[tid * 4];
  float ssq = v.x*v.x + v.y*v.y + v.z*v.z + v.w*v.w;
  #pragma unroll
  for (int off = 32; off > 0; off >>= 1) ssq += __shfl_down(ssq, off);
  __shared__ float red[4];
  int lane = tid & 63, wv = tid >> 6;
  if (lane == 0) red[wv] = ssq;
  __syncthreads();
  if (tid == 0) {
    float s = red[0] + red[1] + red[2] + red[3];
    sc[row] = rsqrtf(s / (float)DMODEL + 1e-4f);
  }
}

// ---------------- diagnostic fallback: out = x (used only if ws too small) ----------------
__global__ __launch_bounds__(256) void copy_x_kernel(const float* __restrict__ x,
                                                     float* __restrict__ out, size_t n) {
  size_t i = (size_t)blockIdx.x * 256 + threadIdx.x;
  if (i < n) out[i] = x[i];
}

// ---------------- fp32 GEMM: C[m,n] = sum_k (A[m,k]*rs[m]*cw[k]) * W[n,k] (+resid) ----
// A: M x K with row stride lda, W: N x K row-major. 128x128 tile, 8x8 microtile, BK=16.
__global__ __launch_bounds__(256) void gemm_nt_kernel(
    const float* __restrict__ A, const float* __restrict__ W,
    float* __restrict__ C, const float* __restrict__ resid,
    const float* __restrict__ rowscale, const float* __restrict__ colw,
    int M, int N, int K, int lda) {
  __shared__ float As[16][128];
  __shared__ float Ws[16][128];
  int tid = threadIdx.x;
  int bm = blockIdx.y * 128;
  int bn = blockIdx.x * 128;
  int tr = tid >> 4, tc = tid & 15;
  float acc[8][8];
  #pragma unroll
  for (int i = 0; i < 8; i++)
    #pragma unroll
    for (int j = 0; j < 8; j++) acc[i][j] = 0.f;

  for (int k0 = 0; k0 < K; k0 += 16) {
    #pragma unroll
    for (int q = 0; q < 2; ++q) {
      int idx = tid + 256 * q;
      int m = idx >> 2;
      int kq = (idx & 3) << 2;
      float4 v = *(const float4*)&A[(size_t)(bm + m) * lda + k0 + kq];
      if (rowscale) {
        float s = rowscale[bm + m];
        float4 w4 = *(const float4*)&colw[k0 + kq];
        v.x *= s * w4.x; v.y *= s * w4.y; v.z *= s * w4.z; v.w *= s * w4.w;
      }
      As[kq+0][m] = v.x; As[kq+1][m] = v.y; As[kq+2][m] = v.z; As[kq+3][m] = v.w;
    }
    #pragma unroll
    for (int q = 0; q < 2; ++q) {
      int idx = tid + 256 * q;
      int n = idx >> 2;
      int kq = (idx & 3) << 2;
      float4 v = make_float4(0.f, 0.f, 0.f, 0.f);
      if (bn + n < N) v = *(const float4*)&W[(size_t)(bn + n) * K + k0 + kq];
      Ws[kq+0][n] = v.x; Ws[kq+1][n] = v.y; Ws[kq+2][n] = v.z; Ws[kq+3][n] = v.w;
    }
    __syncthreads();
    #pragma unroll
    for (int k = 0; k < 16; ++k) {
      float a[8], b[8];
      *(float4*)&a[0] = *(const float4*)&As[k][tr*8];
      *(float4*)&a[4] = *(const float4*)&As[k][tr*8+4];
      *(float4*)&b[0] = *(const float4*)&Ws[k][tc*8];
      *(float4*)&b[4] = *(const float4*)&Ws[k][tc*8+4];
      #pragma unroll
      for (int i = 0; i < 8; i++)
        #pragma unroll
        for (int j = 0; j < 8; j++) acc[i][j] = fmaf(a[i], b[j], acc[i][j]);
    }
    __syncthreads();
  }
  #pragma unroll
  for (int i = 0; i < 8; i++) {
    int m = bm + tr*8 + i;
    #pragma unroll
    for (int jq = 0; jq < 2; jq++) {
      int n = bn + tc*8 + jq*4;
      if (n < N) {
        float4 v;
        v.x = acc[i][jq*4+0]; v.y = acc[i][jq*4+1];
        v.z = acc[i][jq*4+2]; v.w = acc[i][jq*4+3];
        size_t off = (size_t)m * N + n;
        if (resid) {
          float4 r = *(const float4*)&resid[off];
          v.x += r.x; v.y += r.y; v.z += r.z; v.w += r.w;
        }
        *(float4*)&C[off] = v;
      }
    }
  }
}

// ---------------- causal depthwise conv (k=4) + bias + silu ----------------
__global__ __launch_bounds__(256) void conv_silu_kernel(
    const float* __restrict__ zxbcdt, const float* __restrict__ conv_w,
    const float* __restrict__ conv_b, float* __restrict__ xBCp) {
  size_t idx = (size_t)blockIdx.x * 256 + threadIdx.x;  // b*L*CONVCH
  int c = (int)(idx % CONVCH);
  int t = (int)((idx / CONVCH) % L_);
  int b = (int)(idx / ((size_t)CONVCH * L_));
  const float* src = zxbcdt + (size_t)(b * L_) * DINPROJ + DINNER + c;
  float w0 = conv_w[c*4+0], w1 = conv_w[c*4+1], w2 = conv_w[c*4+2], w3 = conv_w[c*4+3];
  float acc = conv_b[c];
  if (t >= 3) acc = fmaf(w0, src[(size_t)(t-3)*DINPROJ], acc);
  if (t >= 2) acc = fmaf(w1, src[(size_t)(t-2)*DINPROJ], acc);
  if (t >= 1) acc = fmaf(w2, src[(size_t)(t-1)*DINPROJ], acc);
  acc = fmaf(w3, src[(size_t)t*DINPROJ], acc);
  xBCp[idx] = silu_f(acc);
}

// ---------------- dt = softplus(dt_raw + bias); dA = exp(-exp(A_log)*dt) ----------------
__global__ __launch_bounds__(256) void dt_prep_kernel(
    const float* __restrict__ zxbcdt, const float* __restrict__ dt_bias,
    const float* __restrict__ A_log, float* __restrict__ dt_out,
    float* __restrict__ dA_out) {
  int idx = blockIdx.x * 256 + threadIdx.x;  // NTOK*NHEADS
  int hh = idx & (NHEADS - 1);
  int row = idx >> 5;
  float v = zxbcdt[(size_t)row * DINPROJ + (DINPROJ - NHEADS) + hh] + dt_bias[hh];
  float sp = (v > 0.f) ? (v + log1pf(expf(-v))) : log1pf(expf(v));
  dt_out[idx] = sp;
  dA_out[idx] = expf(-expf(A_log[hh]) * sp);
}

// ---------------- sequential SSM scan: one workgroup per (b,h) ----------------
// thread layout: wave = n-quarter (32 states), lane = p (headdim). 32 f32 state/thread.
// Writes y into the (dead after conv) xBC slice of zxbcdt: cols [DINNER, 2*DINNER).
__global__ __launch_bounds__(256) void scan_kernel(
    const float* __restrict__ xBCp, const float* __restrict__ dtv,
    const float* __restrict__ dAv, const float* __restrict__ Dp,
    float* __restrict__ ydst /* = zxbcdt */) {
  int b = blockIdx.x >> 5;
  int h = blockIdx.x & 31;
  int tid = threadIdx.x;
  int wave = tid >> 6;
  int lane = tid & 63;  // = p
  __shared__ float BCs[256];     // [0,128)=B, [128,256)=C
  __shared__ float xs_s[HEADDIM];
  __shared__ float yred[4][64];
  float hreg[32];
  #pragma unroll
  for (int i = 0; i < 32; i++) hreg[i] = 0.f;
  float Dh = Dp[h];
  const float* rowbase = xBCp + (size_t)(b * L_) * CONVCH;
  const size_t dtbase = (size_t)(b * L_) * NHEADS + h;
  int nb = wave * 32;

  // prefetch t=0 into registers
  float cBC = rowbase[DINNER + tid];          // works for both B and C halves
  float cx  = (tid < HEADDIM) ? rowbase[h * HEADDIM + tid] : 0.f;
  float cdA = dAv[dtbase];
  float cdt = dtv[dtbase];

  for (int t = 0; t < L_; ++t) {
    __syncthreads();                 // previous iter's LDS consumers done
    BCs[tid] = cBC;
    if (tid < HEADDIM) xs_s[tid] = cx;
    __syncthreads();
    float dA_t = cdA, dt_t = cdt;
    if (t + 1 < L_) {                // register prefetch of t+1 (hidden under compute)
      const float* row = rowbase + (size_t)(t + 1) * CONVCH;
      cBC = row[DINNER + tid];
      if (tid < HEADDIM) cx = row[h * HEADDIM + tid];
      cdA = dAv[dtbase + (size_t)(t + 1) * NHEADS];
      cdt = dtv[dtbase + (size_t)(t + 1) * NHEADS];
    }
    float xp = xs_s[lane];
    float dtx = dt_t * xp;
    float yp = 0.f;
    #pragma unroll
    for (int i = 0; i < 8; ++i) {
      float4 bb = *(const float4*)&BCs[nb + 4*i];        // broadcast reads
      float4 cc = *(const float4*)&BCs[128 + nb + 4*i];
      float h0 = fmaf(dA_t, hreg[4*i+0], dtx*bb.x); hreg[4*i+0] = h0; yp = fmaf(h0, cc.x, yp);
      float h1 = fmaf(dA_t, hreg[4*i+1], dtx*bb.y); hreg[4*i+1] = h1; yp = fmaf(h1, cc.y, yp);
      float h2 = fmaf(dA_t, hreg[4*i+2], dtx*bb.z); hreg[4*i+2] = h2; yp = fmaf(h2, cc.z, yp);
      float h3 = fmaf(dA_t, hreg[4*i+3], dtx*bb.w); hreg[4*i+3] = h3; yp = fmaf(h3, cc.w, yp);
    }
    yred[wave][lane] = yp;
    __syncthreads();
    if (tid < 64) {
      float s = yred[0][lane] + yred[1][lane] + yred[2][lane] + yred[3][lane];
      ydst[((size_t)(b * L_) + t) * DINPROJ + DINNER + h * HEADDIM + lane] = fmaf(Dh, xp, s);
    }
  }
}

// ---------------- gate with silu(z) + RMSNorm (in-place on y slice of zxbcdt) ----------------
__global__ __launch_bounds__(256) void gate_rmsnorm_kernel(
    float* __restrict__ zxbcdt, const float* __restrict__ ssm_w) {
  int row = blockIdx.x;
  float* yr = zxbcdt + (size_t)row * DINPROJ + DINNER;   // y lives in xBC slice
  const float* zr = zxbcdt + (size_t)row * DINPROJ;      // z slice
  int tid = threadIdx.x;
  float vals[8];
  float ssq = 0.f;
  #pragma unroll
  for (int q = 0; q < 2; ++q) {
    int col = q * 1024 + tid * 4;
    float4 yv = *(const float4*)&yr[col];
    float4 zv = *(const float4*)&zr[col];
    float g0 = yv.x * silu_f(zv.x);
    float g1 = yv.y * silu_f(zv.y);
    float g2 = yv.z * silu_f(zv.z);
    float g3 = yv.w * silu_f(zv.w);
    vals[q*4+0] = g0; vals[q*4+1] = g1; vals[q*4+2] = g2; vals[q*4+3] = g3;
    ssq += g0*g0 + g1*g1 + g2*g2 + g3*g3;
  }
  #pragma unroll
  for (int off = 32; off > 0; off >>= 1) ssq += __shfl_down(ssq, off);
  __shared__ float red[4];
  __shared__ float stot;
  int lane = tid & 63, wv = tid >> 6;
  if (lane == 0) red[wv] = ssq;
  __syncthreads();
  if (tid == 0) stot = red[0] + red[1] + red[2] + red[3];
  __syncthreads();
  float scale = rsqrtf(stot / (float)DINNER + 1e-5f);
  #pragma unroll
  for (int q = 0; q < 2; ++q) {
    int col = q * 1024 + tid * 4;
    float4 w4 = *(const float4*)&ssm_w[col];
    float4 o;
    o.x = vals[q*4+0] * scale * w4.x;
    o.y = vals[q*4+1] * scale * w4.y;
    o.z = vals[q*4+2] * scale * w4.z;
    o.w = vals[q*4+3] * scale * w4.w;
    *(float4*)&yr[col] = o;
  }
}

extern "C" void kernel_launch(void* const* d_in, const int* in_sizes, int n_in,
                              void* d_out, int out_size, void* d_ws, size_t ws_size,
                              hipStream_t stream) {
  const float* x          = (const float*)d_in[0];
  const float* norm_w     = (const float*)d_in[1];
  const float* in_proj_w  = (const float*)d_in[2];
  const float* conv_w     = (const float*)d_in[3];
  const float* conv_b     = (const float*)d_in[4];
  const float* dt_bias    = (const float*)d_in[5];
  const float* A_log      = (const float*)d_in[6];
  const float* Dp         = (const float*)d_in[7];
  const float* ssm_norm_w = (const float*)d_in[8];
  const float* out_proj_w = (const float*)d_in[9];
  float* out = (float*)d_out;

  // workspace layout (fp32):
  //   sc      NTOK                    =     8,192
  //   zxbcdt  NTOK*DINPROJ            = 35,913,728   (z | xBC->y | dt)
  //   xBCp    NTOK*CONVCH             = 18,874,368
  //   dtb     NTOK*NHEADS             =    262,144
  //   dAb     NTOK*NHEADS             =    262,144
  // total 55,320,576 floats = 221,282,304 bytes (~211 MiB)
  const size_t needed = ((size_t)NTOK + (size_t)NTOK*DINPROJ + (size_t)NTOK*CONVCH
                         + 2u*(size_t)NTOK*NHEADS) * sizeof(float);
  if (ws_size < needed) {
    // Diagnostic fallback: finite wrong output instead of a GPU fault.
    size_t n = (size_t)NTOK * DMODEL;
    copy_x_kernel<<<(int)((n + 255) / 256), 256, 0, stream>>>(x, out, n);
    return;
  }

  float* ws     = (float*)d_ws;
  float* sc     = ws;
  float* zxbcdt = sc + NTOK;
  float* xBCp   = zxbcdt + (size_t)NTOK * DINPROJ;
  float* dtb    = xBCp + (size_t)NTOK * CONVCH;
  float* dAb    = dtb + (size_t)NTOK * NHEADS;

  rms_scale_kernel<<<NTOK, 256, 0, stream>>>(x, sc);
  gemm_nt_kernel<<<dim3((DINPROJ + 127) / 128, NTOK / 128), 256, 0, stream>>>(
      x, in_proj_w, zxbcdt, nullptr, sc, norm_w, NTOK, DINPROJ, DMODEL, DMODEL);
  conv_silu_kernel<<<(int)(((size_t)NTOK * CONVCH) / 256), 256, 0, stream>>>(
      zxbcdt, conv_w, conv_b, xBCp);
  dt_prep_kernel<<<(NTOK * NHEADS) / 256, 256, 0, stream>>>(
      zxbcdt, dt_bias, A_log, dtb, dAb);
  scan_kernel<<<B_ * NHEADS, 256, 0, stream>>>(xBCp, dtb, dAb, Dp, zxbcdt);
  gate_rmsnorm_kernel<<<NTOK, 256, 0, stream>>>(zxbcdt, ssm_norm_w);
  gemm_nt_kernel<<<dim3(DMODEL / 128, NTOK / 128), 256, 0, stream>>>(
      zxbcdt + DINNER, out_proj_w, out, x, nullptr, nullptr, NTOK, DMODEL, DINNER, DINPROJ);
}

// Round 4
// 1997.217 us; speedup vs baseline: 1.6836x; 1.6836x over previous
//
#include <hip/hip_runtime.h>
#include <hip/hip_bf16.h>
#include <math.h>

#define B_      4
#define L_      2048
#define DMODEL  1024
#define DINNER  2048
#define DSTATE  128
#define NHEADS  32
#define HEADDIM 64
#define DINPROJ 4384   // 2*DINNER + 2*DSTATE + NHEADS
#define CONVCH  2304   // DINNER + 2*DSTATE
#define NTOK    (B_*L_)

#define CHUNK   256
#define NCHUNK  (L_/CHUNK)        // 8
#define TB      8                 // time-steps per LDS stage
#define SBLKS   (B_*NHEADS*(NCHUNK-1))   // 896 stored chunk states

__device__ __forceinline__ float silu_f(float v) {
  return v / (1.0f + __expf(-v));
}

// ---------------- RMSNorm row scale (fused into GEMM1 A-load) ----------------
__global__ __launch_bounds__(256) void rms_scale_kernel(const float* __restrict__ x,
                                                        float* __restrict__ sc) {
  int row = blockIdx.x;
  const float* xr = x + (size_t)row * DMODEL;
  int tid = threadIdx.x;
  float4 v = *(const float4*)&xr[tid * 4];
  float ssq = v.x*v.x + v.y*v.y + v.z*v.z + v.w*v.w;
  #pragma unroll
  for (int off = 32; off > 0; off >>= 1) ssq += __shfl_down(ssq, off);
  __shared__ float red[4];
  int lane = tid & 63, wv = tid >> 6;
  if (lane == 0) red[wv] = ssq;
  __syncthreads();
  if (tid == 0) {
    float s = red[0] + red[1] + red[2] + red[3];
    sc[row] = rsqrtf(s / (float)DMODEL + 1e-4f);
  }
}

// ---------------- diagnostic fallback: out = x ----------------
__global__ __launch_bounds__(256) void copy_x_kernel(const float* __restrict__ x,
                                                     float* __restrict__ out, size_t n) {
  size_t i = (size_t)blockIdx.x * 256 + threadIdx.x;
  if (i < n) out[i] = x[i];
}

// ---------------- fp32 GEMM: C[m,n] = sum_k (A[m,k]*rs[m]*cw[k]) * W[n,k] (+resid) ----
__global__ __launch_bounds__(256) void gemm_nt_kernel(
    const float* __restrict__ A, const float* __restrict__ W,
    float* __restrict__ C, const float* __restrict__ resid,
    const float* __restrict__ rowscale, const float* __restrict__ colw,
    int M, int N, int K, int lda) {
  __shared__ float As[16][128];
  __shared__ float Ws[16][128];
  int tid = threadIdx.x;
  int bm = blockIdx.y * 128;
  int bn = blockIdx.x * 128;
  int tr = tid >> 4, tc = tid & 15;
  float acc[8][8];
  #pragma unroll
  for (int i = 0; i < 8; i++)
    #pragma unroll
    for (int j = 0; j < 8; j++) acc[i][j] = 0.f;

  for (int k0 = 0; k0 < K; k0 += 16) {
    #pragma unroll
    for (int q = 0; q < 2; ++q) {
      int idx = tid + 256 * q;
      int m = idx >> 2;
      int kq = (idx & 3) << 2;
      float4 v = *(const float4*)&A[(size_t)(bm + m) * lda + k0 + kq];
      if (rowscale) {
        float s = rowscale[bm + m];
        float4 w4 = *(const float4*)&colw[k0 + kq];
        v.x *= s * w4.x; v.y *= s * w4.y; v.z *= s * w4.z; v.w *= s * w4.w;
      }
      As[kq+0][m] = v.x; As[kq+1][m] = v.y; As[kq+2][m] = v.z; As[kq+3][m] = v.w;
    }
    #pragma unroll
    for (int q = 0; q < 2; ++q) {
      int idx = tid + 256 * q;
      int n = idx >> 2;
      int kq = (idx & 3) << 2;
      float4 v = make_float4(0.f, 0.f, 0.f, 0.f);
      if (bn + n < N) v = *(const float4*)&W[(size_t)(bn + n) * K + k0 + kq];
      Ws[kq+0][n] = v.x; Ws[kq+1][n] = v.y; Ws[kq+2][n] = v.z; Ws[kq+3][n] = v.w;
    }
    __syncthreads();
    #pragma unroll
    for (int k = 0; k < 16; ++k) {
      float a[8], b[8];
      *(float4*)&a[0] = *(const float4*)&As[k][tr*8];
      *(float4*)&a[4] = *(const float4*)&As[k][tr*8+4];
      *(float4*)&b[0] = *(const float4*)&Ws[k][tc*8];
      *(float4*)&b[4] = *(const float4*)&Ws[k][tc*8+4];
      #pragma unroll
      for (int i = 0; i < 8; i++)
        #pragma unroll
        for (int j = 0; j < 8; j++) acc[i][j] = fmaf(a[i], b[j], acc[i][j]);
    }
    __syncthreads();
  }
  #pragma unroll
  for (int i = 0; i < 8; i++) {
    int m = bm + tr*8 + i;
    #pragma unroll
    for (int jq = 0; jq < 2; jq++) {
      int n = bn + tc*8 + jq*4;
      if (n < N) {
        float4 v;
        v.x = acc[i][jq*4+0]; v.y = acc[i][jq*4+1];
        v.z = acc[i][jq*4+2]; v.w = acc[i][jq*4+3];
        size_t off = (size_t)m * N + n;
        if (resid) {
          float4 r = *(const float4*)&resid[off];
          v.x += r.x; v.y += r.y; v.z += r.z; v.w += r.w;
        }
        *(float4*)&C[off] = v;
      }
    }
  }
}

// ---------------- causal depthwise conv (k=4) + bias + silu ----------------
__global__ __launch_bounds__(256) void conv_silu_kernel(
    const float* __restrict__ zxbcdt, const float* __restrict__ conv_w,
    const float* __restrict__ conv_b, float* __restrict__ xBCp) {
  size_t idx = (size_t)blockIdx.x * 256 + threadIdx.x;  // b*L*CONVCH
  int c = (int)(idx % CONVCH);
  int t = (int)((idx / CONVCH) % L_);
  int b = (int)(idx / ((size_t)CONVCH * L_));
  const float* src = zxbcdt + (size_t)(b * L_) * DINPROJ + DINNER + c;
  float w0 = conv_w[c*4+0], w1 = conv_w[c*4+1], w2 = conv_w[c*4+2], w3 = conv_w[c*4+3];
  float acc = conv_b[c];
  if (t >= 3) acc = fmaf(w0, src[(size_t)(t-3)*DINPROJ], acc);
  if (t >= 2) acc = fmaf(w1, src[(size_t)(t-2)*DINPROJ], acc);
  if (t >= 1) acc = fmaf(w2, src[(size_t)(t-1)*DINPROJ], acc);
  acc = fmaf(w3, src[(size_t)t*DINPROJ], acc);
  xBCp[idx] = silu_f(acc);
}

// ---------------- dt = softplus(dt_raw + bias); dA = exp(-exp(A_log)*dt) ----------------
__global__ __launch_bounds__(256) void dt_prep_kernel(
    const float* __restrict__ zxbcdt, const float* __restrict__ dt_bias,
    const float* __restrict__ A_log, float* __restrict__ dt_out,
    float* __restrict__ dA_out) {
  int idx = blockIdx.x * 256 + threadIdx.x;  // NTOK*NHEADS
  int hh = idx & (NHEADS - 1);
  int row = idx >> 5;
  float v = zxbcdt[(size_t)row * DINPROJ + (DINPROJ - NHEADS) + hh] + dt_bias[hh];
  float sp = (v > 0.f) ? (v + log1pf(expf(-v))) : log1pf(expf(v));
  dt_out[idx] = sp;
  dA_out[idx] = expf(-expf(A_log[hh]) * sp);
}

// ============ Chunked scan pass A: zero-init chunk states ============
// grid: bh*(NCHUNK-1)+c (chunks 0..NCHUNK-2). thread (wave,lane): p=lane, n=wave*32+i.
// Sbuf float4-slot mapping: slot = blk*2048 + j*256 + tid  <->  S[4j..4j+3]
__global__ __launch_bounds__(256) void chunk_state_kernel(
    const float* __restrict__ xBCp, const float* __restrict__ dtv,
    const float* __restrict__ dAv, float4* __restrict__ Sbuf4,
    float* __restrict__ Pbuf) {
  int blk = blockIdx.x;
  int c  = blk % (NCHUNK - 1);
  int bh = blk / (NCHUNK - 1);
  int b = bh >> 5, h = bh & 31;
  int tid = threadIdx.x;
  int wave = tid >> 6, lane = tid & 63;
  __shared__ __align__(16) float Bs[TB][DSTATE];
  __shared__ __align__(16) float xs[TB][HEADDIM];
  __shared__ float dAs[TB], dts[TB];
  float S[32];
  #pragma unroll
  for (int i = 0; i < 32; i++) S[i] = 0.f;
  float pdec = 1.f;
  const float* rowbase = xBCp + ((size_t)(b * L_) + c * CHUNK) * CONVCH;
  const size_t dtbase = ((size_t)(b * L_) + (size_t)c * CHUNK) * NHEADS + h;
  int nb = wave * 32;

  for (int t0 = 0; t0 < CHUNK; t0 += TB) {
    __syncthreads();
    #pragma unroll
    for (int i = 0; i < 4; ++i) {           // B: TB*128
      int idx = i * 256 + tid;
      int tt = idx >> 7, n = idx & 127;
      Bs[tt][n] = rowbase[(size_t)(t0 + tt) * CONVCH + DINNER + n];
    }
    #pragma unroll
    for (int i = 0; i < 2; ++i) {           // x: TB*64
      int idx = i * 256 + tid;
      int tt = idx >> 6, p = idx & 63;
      xs[tt][p] = rowbase[(size_t)(t0 + tt) * CONVCH + h * HEADDIM + p];
    }
    if (tid < TB) dAs[tid] = dAv[dtbase + (size_t)(t0 + tid) * NHEADS];
    else if (tid < 2 * TB) dts[tid - TB] = dtv[dtbase + (size_t)(t0 + tid - TB) * NHEADS];
    __syncthreads();
    #pragma unroll
    for (int tt = 0; tt < TB; ++tt) {
      float dA = dAs[tt];
      float dtx = dts[tt] * xs[tt][lane];
      pdec *= dA;
      #pragma unroll
      for (int j = 0; j < 8; ++j) {
        float4 bb = *(const float4*)&Bs[tt][nb + 4 * j];
        S[4*j+0] = fmaf(dA, S[4*j+0], dtx * bb.x);
        S[4*j+1] = fmaf(dA, S[4*j+1], dtx * bb.y);
        S[4*j+2] = fmaf(dA, S[4*j+2], dtx * bb.z);
        S[4*j+3] = fmaf(dA, S[4*j+3], dtx * bb.w);
      }
    }
  }
  size_t base4 = (size_t)blk * 2048;
  #pragma unroll
  for (int j = 0; j < 8; ++j)
    Sbuf4[base4 + (size_t)j * 256 + tid] = make_float4(S[4*j], S[4*j+1], S[4*j+2], S[4*j+3]);
  if (tid == 0) Pbuf[blk] = pdec;
}

// ============ Pass B: serial prefix over chunks (slot c becomes Sinit(c+1)) ============
__global__ __launch_bounds__(256) void combine_kernel(float4* __restrict__ Sbuf4,
                                                      const float* __restrict__ Pbuf) {
  int bh = blockIdx.x;
  int tid = threadIdx.x;
  float4 run[8];
  #pragma unroll
  for (int j = 0; j < 8; ++j) run[j] = make_float4(0.f, 0.f, 0.f, 0.f);
  for (int c = 0; c < NCHUNK - 1; ++c) {
    size_t base4 = (size_t)(bh * (NCHUNK - 1) + c) * 2048;
    float P = Pbuf[bh * (NCHUNK - 1) + c];
    #pragma unroll
    for (int j = 0; j < 8; ++j) {
      float4 v = Sbuf4[base4 + (size_t)j * 256 + tid];
      float4 nr;
      nr.x = fmaf(P, run[j].x, v.x);
      nr.y = fmaf(P, run[j].y, v.y);
      nr.z = fmaf(P, run[j].z, v.z);
      nr.w = fmaf(P, run[j].w, v.w);
      Sbuf4[base4 + (size_t)j * 256 + tid] = nr;
      run[j] = nr;
    }
  }
}

// ============ Pass C: y-producing recurrence per chunk, seeded with Sinit ============
__global__ __launch_bounds__(256) void chunk_scan_kernel(
    const float* __restrict__ xBCp, const float* __restrict__ dtv,
    const float* __restrict__ dAv, const float* __restrict__ Dp,
    const float4* __restrict__ Sbuf4, float* __restrict__ ydst /* = zxbcdt */) {
  int blk = blockIdx.x;                 // bh*NCHUNK + c
  int c  = blk & (NCHUNK - 1);
  int bh = blk >> 3;
  int b = bh >> 5, h = bh & 31;
  int tid = threadIdx.x;
  int wave = tid >> 6, lane = tid & 63;
  __shared__ __align__(16) float BCs[TB][2 * DSTATE];   // [.. ,0:128)=B, [128:256)=C
  __shared__ __align__(16) float xs[TB][HEADDIM];
  __shared__ float dAs[TB], dts[TB];
  __shared__ float yred[4][TB][HEADDIM];
  float S[32];
  if (c > 0) {
    size_t base4 = (size_t)(bh * (NCHUNK - 1) + (c - 1)) * 2048;
    #pragma unroll
    for (int j = 0; j < 8; ++j) {
      float4 v = Sbuf4[base4 + (size_t)j * 256 + tid];
      S[4*j+0] = v.x; S[4*j+1] = v.y; S[4*j+2] = v.z; S[4*j+3] = v.w;
    }
  } else {
    #pragma unroll
    for (int i = 0; i < 32; i++) S[i] = 0.f;
  }
  float Dh = Dp[h];
  const float* rowbase = xBCp + ((size_t)(b * L_) + c * CHUNK) * CONVCH;
  const size_t dtbase = ((size_t)(b * L_) + (size_t)c * CHUNK) * NHEADS + h;
  int nb = wave * 32;

  for (int t0 = 0; t0 < CHUNK; t0 += TB) {
    __syncthreads();                         // protects BCs/xs (y-write of prev batch done)
    #pragma unroll
    for (int i = 0; i < 8; ++i) {            // B,C: TB*256
      int idx = i * 256 + tid;
      int tt = idx >> 8, col = idx & 255;
      BCs[tt][col] = rowbase[(size_t)(t0 + tt) * CONVCH + DINNER + col];
    }
    #pragma unroll
    for (int i = 0; i < 2; ++i) {            // x: TB*64
      int idx = i * 256 + tid;
      int tt = idx >> 6, p = idx & 63;
      xs[tt][p] = rowbase[(size_t)(t0 + tt) * CONVCH + h * HEADDIM + p];
    }
    if (tid < TB) dAs[tid] = dAv[dtbase + (size_t)(t0 + tid) * NHEADS];
    else if (tid < 2 * TB) dts[tid - TB] = dtv[dtbase + (size_t)(t0 + tid - TB) * NHEADS];
    __syncthreads();
    #pragma unroll
    for (int tt = 0; tt < TB; ++tt) {
      float dA = dAs[tt];
      float dtx = dts[tt] * xs[tt][lane];
      float yp0 = 0.f, yp1 = 0.f, yp2 = 0.f, yp3 = 0.f;
      #pragma unroll
      for (int j = 0; j < 8; ++j) {
        float4 bb = *(const float4*)&BCs[tt][nb + 4 * j];
        float4 cc = *(const float4*)&BCs[tt][DSTATE + nb + 4 * j];
        float h0 = fmaf(dA, S[4*j+0], dtx * bb.x); S[4*j+0] = h0; yp0 = fmaf(h0, cc.x, yp0);
        float h1 = fmaf(dA, S[4*j+1], dtx * bb.y); S[4*j+1] = h1; yp1 = fmaf(h1, cc.y, yp1);
        float h2 = fmaf(dA, S[4*j+2], dtx * bb.z); S[4*j+2] = h2; yp2 = fmaf(h2, cc.z, yp2);
        float h3 = fmaf(dA, S[4*j+3], dtx * bb.w); S[4*j+3] = h3; yp3 = fmaf(h3, cc.w, yp3);
      }
      yred[wave][tt][lane] = (yp0 + yp1) + (yp2 + yp3);
    }
    __syncthreads();
    #pragma unroll
    for (int i = 0; i < 2; ++i) {            // y-write: TB*64 outputs
      int idx = i * 256 + tid;
      int tt = idx >> 6, p = idx & 63;
      float s = (yred[0][tt][p] + yred[1][tt][p]) + (yred[2][tt][p] + yred[3][tt][p]);
      int t = c * CHUNK + t0 + tt;
      ydst[((size_t)(b * L_) + t) * DINPROJ + DINNER + h * HEADDIM + p] =
          fmaf(Dh, xs[tt][p], s);
    }
  }
}

// ---------------- legacy serial scan (fallback if ws too small for Sbuf) ----------------
__global__ __launch_bounds__(256) void scan_kernel(
    const float* __restrict__ xBCp, const float* __restrict__ dtv,
    const float* __restrict__ dAv, const float* __restrict__ Dp,
    float* __restrict__ ydst) {
  int b = blockIdx.x >> 5;
  int h = blockIdx.x & 31;
  int tid = threadIdx.x;
  int wave = tid >> 6;
  int lane = tid & 63;
  __shared__ float BCs[256];
  __shared__ float xs_s[HEADDIM];
  __shared__ float yred[4][64];
  float hreg[32];
  #pragma unroll
  for (int i = 0; i < 32; i++) hreg[i] = 0.f;
  float Dh = Dp[h];
  const float* rowbase = xBCp + (size_t)(b * L_) * CONVCH;
  const size_t dtbase = (size_t)(b * L_) * NHEADS + h;
  int nb = wave * 32;
  float cBC = rowbase[DINNER + tid];
  float cx  = (tid < HEADDIM) ? rowbase[h * HEADDIM + tid] : 0.f;
  float cdA = dAv[dtbase];
  float cdt = dtv[dtbase];
  for (int t = 0; t < L_; ++t) {
    __syncthreads();
    BCs[tid] = cBC;
    if (tid < HEADDIM) xs_s[tid] = cx;
    __syncthreads();
    float dA_t = cdA, dt_t = cdt;
    if (t + 1 < L_) {
      const float* row = rowbase + (size_t)(t + 1) * CONVCH;
      cBC = row[DINNER + tid];
      if (tid < HEADDIM) cx = row[h * HEADDIM + tid];
      cdA = dAv[dtbase + (size_t)(t + 1) * NHEADS];
      cdt = dtv[dtbase + (size_t)(t + 1) * NHEADS];
    }
    float xp = xs_s[lane];
    float dtx = dt_t * xp;
    float yp = 0.f;
    #pragma unroll
    for (int i = 0; i < 8; ++i) {
      float4 bb = *(const float4*)&BCs[nb + 4*i];
      float4 cc = *(const float4*)&BCs[128 + nb + 4*i];
      float h0 = fmaf(dA_t, hreg[4*i+0], dtx*bb.x); hreg[4*i+0] = h0; yp = fmaf(h0, cc.x, yp);
      float h1 = fmaf(dA_t, hreg[4*i+1], dtx*bb.y); hreg[4*i+1] = h1; yp = fmaf(h1, cc.y, yp);
      float h2 = fmaf(dA_t, hreg[4*i+2], dtx*bb.z); hreg[4*i+2] = h2; yp = fmaf(h2, cc.z, yp);
      float h3 = fmaf(dA_t, hreg[4*i+3], dtx*bb.w); hreg[4*i+3] = h3; yp = fmaf(h3, cc.w, yp);
    }
    yred[wave][lane] = yp;
    __syncthreads();
    if (tid < 64) {
      float s = yred[0][lane] + yred[1][lane] + yred[2][lane] + yred[3][lane];
      ydst[((size_t)(b * L_) + t) * DINPROJ + DINNER + h * HEADDIM + lane] = fmaf(Dh, xp, s);
    }
  }
}

// ---------------- gate with silu(z) + RMSNorm (in-place on y slice of zxbcdt) ----------------
__global__ __launch_bounds__(256) void gate_rmsnorm_kernel(
    float* __restrict__ zxbcdt, const float* __restrict__ ssm_w) {
  int row = blockIdx.x;
  float* yr = zxbcdt + (size_t)row * DINPROJ + DINNER;
  const float* zr = zxbcdt + (size_t)row * DINPROJ;
  int tid = threadIdx.x;
  float vals[8];
  float ssq = 0.f;
  #pragma unroll
  for (int q = 0; q < 2; ++q) {
    int col = q * 1024 + tid * 4;
    float4 yv = *(const float4*)&yr[col];
    float4 zv = *(const float4*)&zr[col];
    float g0 = yv.x * silu_f(zv.x);
    float g1 = yv.y * silu_f(zv.y);
    float g2 = yv.z * silu_f(zv.z);
    float g3 = yv.w * silu_f(zv.w);
    vals[q*4+0] = g0; vals[q*4+1] = g1; vals[q*4+2] = g2; vals[q*4+3] = g3;
    ssq += g0*g0 + g1*g1 + g2*g2 + g3*g3;
  }
  #pragma unroll
  for (int off = 32; off > 0; off >>= 1) ssq += __shfl_down(ssq, off);
  __shared__ float red[4];
  __shared__ float stot;
  int lane = tid & 63, wv = tid >> 6;
  if (lane == 0) red[wv] = ssq;
  __syncthreads();
  if (tid == 0) stot = red[0] + red[1] + red[2] + red[3];
  __syncthreads();
  float scale = rsqrtf(stot / (float)DINNER + 1e-5f);
  #pragma unroll
  for (int q = 0; q < 2; ++q) {
    int col = q * 1024 + tid * 4;
    float4 w4 = *(const float4*)&ssm_w[col];
    float4 o;
    o.x = vals[q*4+0] * scale * w4.x;
    o.y = vals[q*4+1] * scale * w4.y;
    o.z = vals[q*4+2] * scale * w4.z;
    o.w = vals[q*4+3] * scale * w4.w;
    *(float4*)&yr[col] = o;
  }
}

extern "C" void kernel_launch(void* const* d_in, const int* in_sizes, int n_in,
                              void* d_out, int out_size, void* d_ws, size_t ws_size,
                              hipStream_t stream) {
  const float* x          = (const float*)d_in[0];
  const float* norm_w     = (const float*)d_in[1];
  const float* in_proj_w  = (const float*)d_in[2];
  const float* conv_w     = (const float*)d_in[3];
  const float* conv_b     = (const float*)d_in[4];
  const float* dt_bias    = (const float*)d_in[5];
  const float* A_log      = (const float*)d_in[6];
  const float* Dp         = (const float*)d_in[7];
  const float* ssm_norm_w = (const float*)d_in[8];
  const float* out_proj_w = (const float*)d_in[9];
  float* out = (float*)d_out;

  // workspace layout (fp32):
  //   sc      NTOK; zxbcdt NTOK*DINPROJ; xBCp NTOK*CONVCH; dtb/dAb NTOK*NHEADS each
  //   Sbuf    SBLKS*8192 (29.4 MB) ; Pbuf SBLKS
  const size_t serialf = (size_t)NTOK + (size_t)NTOK*DINPROJ + (size_t)NTOK*CONVCH
                       + 2u*(size_t)NTOK*NHEADS;
  const size_t need_serial = serialf * sizeof(float);
  const size_t need_chunk  = (serialf + (size_t)SBLKS*8192 + SBLKS) * sizeof(float);
  if (ws_size < need_serial) {
    size_t n = (size_t)NTOK * DMODEL;
    copy_x_kernel<<<(int)((n + 255) / 256), 256, 0, stream>>>(x, out, n);
    return;
  }

  float* ws     = (float*)d_ws;
  float* sc     = ws;
  float* zxbcdt = sc + NTOK;
  float* xBCp   = zxbcdt + (size_t)NTOK * DINPROJ;
  float* dtb    = xBCp + (size_t)NTOK * CONVCH;
  float* dAb    = dtb + (size_t)NTOK * NHEADS;
  float* Sbuf   = dAb + (size_t)NTOK * NHEADS;
  float* Pbuf   = Sbuf + (size_t)SBLKS * 8192;

  rms_scale_kernel<<<NTOK, 256, 0, stream>>>(x, sc);
  gemm_nt_kernel<<<dim3((DINPROJ + 127) / 128, NTOK / 128), 256, 0, stream>>>(
      x, in_proj_w, zxbcdt, nullptr, sc, norm_w, NTOK, DINPROJ, DMODEL, DMODEL);
  conv_silu_kernel<<<(int)(((size_t)NTOK * CONVCH) / 256), 256, 0, stream>>>(
      zxbcdt, conv_w, conv_b, xBCp);
  dt_prep_kernel<<<(NTOK * NHEADS) / 256, 256, 0, stream>>>(
      zxbcdt, dt_bias, A_log, dtb, dAb);
  if (ws_size >= need_chunk) {
    chunk_state_kernel<<<SBLKS, 256, 0, stream>>>(xBCp, dtb, dAb, (float4*)Sbuf, Pbuf);
    combine_kernel<<<B_ * NHEADS, 256, 0, stream>>>((float4*)Sbuf, Pbuf);
    chunk_scan_kernel<<<B_ * NHEADS * NCHUNK, 256, 0, stream>>>(
        xBCp, dtb, dAb, Dp, (const float4*)Sbuf, zxbcdt);
  } else {
    scan_kernel<<<B_ * NHEADS, 256, 0, stream>>>(xBCp, dtb, dAb, Dp, zxbcdt);
  }
  gate_rmsnorm_kernel<<<NTOK, 256, 0, stream>>>(zxbcdt, ssm_norm_w);
  gemm_nt_kernel<<<dim3(DMODEL / 128, NTOK / 128), 256, 0, stream>>>(
      zxbcdt + DINNER, out_proj_w, out, x, nullptr, nullptr, NTOK, DMODEL, DINNER, DINPROJ);
}

// Round 12
// 1055.153 us; speedup vs baseline: 3.1867x; 1.8928x over previous
//
#include <hip/hip_runtime.h>
#include <hip/hip_bf16.h>
#include <math.h>

#define B_      4
#define L_      2048
#define DMODEL  1024
#define DINNER  2048
#define DSTATE  128
#define NHEADS  32
#define HEADDIM 64
#define DINPROJ 4384   // 2*DINNER + 2*DSTATE + NHEADS
#define CONVCH  2304   // DINNER + 2*DSTATE
#define NTOK    (B_*L_)

#define CHUNK   256
#define NCHUNK  (L_/CHUNK)        // 8
#define TB      8                 // time-steps per LDS stage
#define SBLKS   (B_*NHEADS*(NCHUNK-1))   // 896 stored chunk states

typedef __bf16 v8bf __attribute__((ext_vector_type(8)));
typedef __bf16 v4bf __attribute__((ext_vector_type(4)));
typedef float  v4f  __attribute__((ext_vector_type(4)));

__device__ __forceinline__ float silu_f(float v) {
  return v / (1.0f + __expf(-v));
}

// ---------------- RMSNorm row scale ----------------
__global__ __launch_bounds__(256) void rms_scale_kernel(const float* __restrict__ x,
                                                        float* __restrict__ sc) {
  int row = blockIdx.x;
  const float* xr = x + (size_t)row * DMODEL;
  int tid = threadIdx.x;
  float4 v = *(const float4*)&xr[tid * 4];
  float ssq = v.x*v.x + v.y*v.y + v.z*v.z + v.w*v.w;
  #pragma unroll
  for (int off = 32; off > 0; off >>= 1) ssq += __shfl_down(ssq, off);
  __shared__ float red[4];
  int lane = tid & 63, wv = tid >> 6;
  if (lane == 0) red[wv] = ssq;
  __syncthreads();
  if (tid == 0) {
    float s = red[0] + red[1] + red[2] + red[3];
    sc[row] = rsqrtf(s / (float)DMODEL + 1e-4f);
  }
}

// ---------------- diagnostic fallback ----------------
__global__ __launch_bounds__(256) void copy_x_kernel(const float* __restrict__ x,
                                                     float* __restrict__ out, size_t n) {
  size_t i = (size_t)blockIdx.x * 256 + threadIdx.x;
  if (i < n) out[i] = x[i];
}

// ---------------- bf16 hi/lo split: A1 = rmsnorm(x) (scale fused) ----------------
__global__ __launch_bounds__(256) void split_a1_kernel(
    const float* __restrict__ x, const float* __restrict__ sc,
    const float* __restrict__ nw, __bf16* __restrict__ hi, __bf16* __restrict__ lo) {
  size_t base = ((size_t)blockIdx.x * 256 + threadIdx.x) * 4;
  int row = (int)(base >> 10);
  int col = (int)(base & 1023);
  float s = sc[row];
  float4 xv = *(const float4*)&x[base];
  float4 wv = *(const float4*)&nw[col];
  float a0 = xv.x * s * wv.x, a1 = xv.y * s * wv.y;
  float a2 = xv.z * s * wv.z, a3 = xv.w * s * wv.w;
  v4bf h, l;
  h[0] = (__bf16)a0; l[0] = (__bf16)(a0 - (float)h[0]);
  h[1] = (__bf16)a1; l[1] = (__bf16)(a1 - (float)h[1]);
  h[2] = (__bf16)a2; l[2] = (__bf16)(a2 - (float)h[2]);
  h[3] = (__bf16)a3; l[3] = (__bf16)(a3 - (float)h[3]);
  *(v4bf*)&hi[base] = h;
  *(v4bf*)&lo[base] = l;
}

// ---------------- bf16 hi/lo split: plain (weights) ----------------
__global__ __launch_bounds__(256) void split_kernel(
    const float* __restrict__ in, __bf16* __restrict__ hi, __bf16* __restrict__ lo) {
  size_t base = ((size_t)blockIdx.x * 256 + threadIdx.x) * 4;
  float4 xv = *(const float4*)&in[base];
  v4bf h, l;
  h[0] = (__bf16)xv.x; l[0] = (__bf16)(xv.x - (float)h[0]);
  h[1] = (__bf16)xv.y; l[1] = (__bf16)(xv.y - (float)h[1]);
  h[2] = (__bf16)xv.z; l[2] = (__bf16)(xv.z - (float)h[2]);
  h[3] = (__bf16)xv.w; l[3] = (__bf16)(xv.w - (float)h[3]);
  *(v4bf*)&hi[base] = h;
  *(v4bf*)&lo[base] = l;
}

// ---------------- bf16x3 MFMA GEMM: C[m,n] = A[m,:]·W[n,:] (+resid) ----------------
// A planes: M x K bf16 (hi,lo). W planes: N x K bf16. C: M x N fp32 dense.
// 128x128 tile, BK=32, 4 waves, each wave 4x4 frags of mfma_f32_16x16x32_bf16.
// LDS rows padded to 40 bf16 (80 B) -> fragment reads are <=2-way (free).
__global__ __launch_bounds__(256) void gemm_mfma_kernel(
    const __bf16* __restrict__ Ahi, const __bf16* __restrict__ Alo,
    const __bf16* __restrict__ Whi, const __bf16* __restrict__ Wlo,
    float* __restrict__ C, const float* __restrict__ resid,
    int M, int N, int K) {
  __shared__ __align__(16) __bf16 Ah[128 * 40];
  __shared__ __align__(16) __bf16 Al[128 * 40];
  __shared__ __align__(16) __bf16 Bh[128 * 40];
  __shared__ __align__(16) __bf16 Bl[128 * 40];
  int tid = threadIdx.x;
  int bm = blockIdx.y * 128;
  int bn = blockIdx.x * 128;
  int w = tid >> 6, lane = tid & 63;
  int wr = w >> 1, wc = w & 1;

  v4f acc[4][4];
  #pragma unroll
  for (int i = 0; i < 4; i++)
    #pragma unroll
    for (int j = 0; j < 4; j++) acc[i][j] = (v4f){0.f, 0.f, 0.f, 0.f};

  v8bf zz;
  #pragma unroll
  for (int z = 0; z < 8; z++) zz[z] = (__bf16)0.f;

  // staging coords (2 chunks of 16B per thread per tile)
  int r0 = tid >> 2,          c0 = tid & 3;
  int r1 = (tid + 256) >> 2,  c1 = (tid + 256) & 3;
  int arow = wr * 64 + (lane & 15);
  int brow = wc * 64 + (lane & 15);
  int koff = (lane >> 4) * 8;

  for (int k0 = 0; k0 < K; k0 += 32) {
    __syncthreads();
    {
      size_t ga0 = (size_t)(bm + r0) * K + k0 + c0 * 8;
      size_t ga1 = (size_t)(bm + r1) * K + k0 + c1 * 8;
      *(v8bf*)&Ah[r0 * 40 + c0 * 8] = *(const v8bf*)&Ahi[ga0];
      *(v8bf*)&Al[r0 * 40 + c0 * 8] = *(const v8bf*)&Alo[ga0];
      *(v8bf*)&Ah[r1 * 40 + c1 * 8] = *(const v8bf*)&Ahi[ga1];
      *(v8bf*)&Al[r1 * 40 + c1 * 8] = *(const v8bf*)&Alo[ga1];
      v8bf b0h = zz, b0l = zz, b1h = zz, b1l = zz;
      if (bn + r0 < N) {
        size_t gb = (size_t)(bn + r0) * K + k0 + c0 * 8;
        b0h = *(const v8bf*)&Whi[gb]; b0l = *(const v8bf*)&Wlo[gb];
      }
      if (bn + r1 < N) {
        size_t gb = (size_t)(bn + r1) * K + k0 + c1 * 8;
        b1h = *(const v8bf*)&Whi[gb]; b1l = *(const v8bf*)&Wlo[gb];
      }
      *(v8bf*)&Bh[r0 * 40 + c0 * 8] = b0h;
      *(v8bf*)&Bl[r0 * 40 + c0 * 8] = b0l;
      *(v8bf*)&Bh[r1 * 40 + c1 * 8] = b1h;
      *(v8bf*)&Bl[r1 * 40 + c1 * 8] = b1l;
    }
    __syncthreads();

    v8bf afh[4], afl[4], bfh[4], bfl[4];
    #pragma unroll
    for (int f = 0; f < 4; ++f) {
      afh[f] = *(const v8bf*)&Ah[(arow + f * 16) * 40 + koff];
      afl[f] = *(const v8bf*)&Al[(arow + f * 16) * 40 + koff];
      bfh[f] = *(const v8bf*)&Bh[(brow + f * 16) * 40 + koff];
      bfl[f] = *(const v8bf*)&Bl[(brow + f * 16) * 40 + koff];
    }
    #pragma unroll
    for (int i = 0; i < 4; ++i)
      #pragma unroll
      for (int j = 0; j < 4; ++j) {
        acc[i][j] = __builtin_amdgcn_mfma_f32_16x16x32_bf16(afh[i], bfh[j], acc[i][j], 0, 0, 0);
        acc[i][j] = __builtin_amdgcn_mfma_f32_16x16x32_bf16(afh[i], bfl[j], acc[i][j], 0, 0, 0);
        acc[i][j] = __builtin_amdgcn_mfma_f32_16x16x32_bf16(afl[i], bfh[j], acc[i][j], 0, 0, 0);
      }
  }

  // epilogue: C/D layout col=lane&15, row=(lane>>4)*4+e  [m89-verified]
  #pragma unroll
  for (int i = 0; i < 4; ++i) {
    int mb = bm + wr * 64 + i * 16 + (lane >> 4) * 4;
    #pragma unroll
    for (int j = 0; j < 4; ++j) {
      int n = bn + wc * 64 + j * 16 + (lane & 15);
      if (n < N) {
        #pragma unroll
        for (int e = 0; e < 4; ++e) {
          size_t off = (size_t)(mb + e) * N + n;
          float v = acc[i][j][e];
          if (resid) v += resid[off];
          C[off] = v;
        }
      }
    }
  }
}

// ---------------- causal depthwise conv (k=4) + bias + silu ----------------
__global__ __launch_bounds__(256) void conv_silu_kernel(
    const float* __restrict__ zxbcdt, const float* __restrict__ conv_w,
    const float* __restrict__ conv_b, float* __restrict__ xBCp) {
  size_t idx = (size_t)blockIdx.x * 256 + threadIdx.x;  // b*L*CONVCH
  int c = (int)(idx % CONVCH);
  int t = (int)((idx / CONVCH) % L_);
  int b = (int)(idx / ((size_t)CONVCH * L_));
  const float* src = zxbcdt + (size_t)(b * L_) * DINPROJ + DINNER + c;
  float w0 = conv_w[c*4+0], w1 = conv_w[c*4+1], w2 = conv_w[c*4+2], w3 = conv_w[c*4+3];
  float acc = conv_b[c];
  if (t >= 3) acc = fmaf(w0, src[(size_t)(t-3)*DINPROJ], acc);
  if (t >= 2) acc = fmaf(w1, src[(size_t)(t-2)*DINPROJ], acc);
  if (t >= 1) acc = fmaf(w2, src[(size_t)(t-1)*DINPROJ], acc);
  acc = fmaf(w3, src[(size_t)t*DINPROJ], acc);
  xBCp[idx] = silu_f(acc);
}

// ---------------- dt = softplus(dt_raw + bias); dA = exp(-exp(A_log)*dt) ----------------
__global__ __launch_bounds__(256) void dt_prep_kernel(
    const float* __restrict__ zxbcdt, const float* __restrict__ dt_bias,
    const float* __restrict__ A_log, float* __restrict__ dt_out,
    float* __restrict__ dA_out) {
  int idx = blockIdx.x * 256 + threadIdx.x;  // NTOK*NHEADS
  int hh = idx & (NHEADS - 1);
  int row = idx >> 5;
  float v = zxbcdt[(size_t)row * DINPROJ + (DINPROJ - NHEADS) + hh] + dt_bias[hh];
  float sp = (v > 0.f) ? (v + log1pf(expf(-v))) : log1pf(expf(v));
  dt_out[idx] = sp;
  dA_out[idx] = expf(-expf(A_log[hh]) * sp);
}

// ============ Chunked scan pass A: zero-init chunk states ============
__global__ __launch_bounds__(256) void chunk_state_kernel(
    const float* __restrict__ xBCp, const float* __restrict__ dtv,
    const float* __restrict__ dAv, float4* __restrict__ Sbuf4,
    float* __restrict__ Pbuf) {
  int blk = blockIdx.x;
  int c  = blk % (NCHUNK - 1);
  int bh = blk / (NCHUNK - 1);
  int b = bh >> 5, h = bh & 31;
  int tid = threadIdx.x;
  int wave = tid >> 6, lane = tid & 63;
  __shared__ __align__(16) float Bs[TB][DSTATE];
  __shared__ __align__(16) float xs[TB][HEADDIM];
  __shared__ float dAs[TB], dts[TB];
  float S[32];
  #pragma unroll
  for (int i = 0; i < 32; i++) S[i] = 0.f;
  float pdec = 1.f;
  const float* rowbase = xBCp + ((size_t)(b * L_) + c * CHUNK) * CONVCH;
  const size_t dtbase = ((size_t)(b * L_) + (size_t)c * CHUNK) * NHEADS + h;
  int nb = wave * 32;

  for (int t0 = 0; t0 < CHUNK; t0 += TB) {
    __syncthreads();
    #pragma unroll
    for (int i = 0; i < 4; ++i) {
      int idx = i * 256 + tid;
      int tt = idx >> 7, n = idx & 127;
      Bs[tt][n] = rowbase[(size_t)(t0 + tt) * CONVCH + DINNER + n];
    }
    #pragma unroll
    for (int i = 0; i < 2; ++i) {
      int idx = i * 256 + tid;
      int tt = idx >> 6, p = idx & 63;
      xs[tt][p] = rowbase[(size_t)(t0 + tt) * CONVCH + h * HEADDIM + p];
    }
    if (tid < TB) dAs[tid] = dAv[dtbase + (size_t)(t0 + tid) * NHEADS];
    else if (tid < 2 * TB) dts[tid - TB] = dtv[dtbase + (size_t)(t0 + tid - TB) * NHEADS];
    __syncthreads();
    #pragma unroll
    for (int tt = 0; tt < TB; ++tt) {
      float dA = dAs[tt];
      float dtx = dts[tt] * xs[tt][lane];
      pdec *= dA;
      #pragma unroll
      for (int j = 0; j < 8; ++j) {
        float4 bb = *(const float4*)&Bs[tt][nb + 4 * j];
        S[4*j+0] = fmaf(dA, S[4*j+0], dtx * bb.x);
        S[4*j+1] = fmaf(dA, S[4*j+1], dtx * bb.y);
        S[4*j+2] = fmaf(dA, S[4*j+2], dtx * bb.z);
        S[4*j+3] = fmaf(dA, S[4*j+3], dtx * bb.w);
      }
    }
  }
  size_t base4 = (size_t)blk * 2048;
  #pragma unroll
  for (int j = 0; j < 8; ++j)
    Sbuf4[base4 + (size_t)j * 256 + tid] = make_float4(S[4*j], S[4*j+1], S[4*j+2], S[4*j+3]);
  if (tid == 0) Pbuf[blk] = pdec;
}

// ============ Pass B: serial prefix over chunks ============
__global__ __launch_bounds__(256) void combine_kernel(float4* __restrict__ Sbuf4,
                                                      const float* __restrict__ Pbuf) {
  int bh = blockIdx.x;
  int tid = threadIdx.x;
  float4 run[8];
  #pragma unroll
  for (int j = 0; j < 8; ++j) run[j] = make_float4(0.f, 0.f, 0.f, 0.f);
  for (int c = 0; c < NCHUNK - 1; ++c) {
    size_t base4 = (size_t)(bh * (NCHUNK - 1) + c) * 2048;
    float P = Pbuf[bh * (NCHUNK - 1) + c];
    #pragma unroll
    for (int j = 0; j < 8; ++j) {
      float4 v = Sbuf4[base4 + (size_t)j * 256 + tid];
      float4 nr;
      nr.x = fmaf(P, run[j].x, v.x);
      nr.y = fmaf(P, run[j].y, v.y);
      nr.z = fmaf(P, run[j].z, v.z);
      nr.w = fmaf(P, run[j].w, v.w);
      Sbuf4[base4 + (size_t)j * 256 + tid] = nr;
      run[j] = nr;
    }
  }
}

// ============ Pass C: y-producing recurrence per chunk ============
__global__ __launch_bounds__(256) void chunk_scan_kernel(
    const float* __restrict__ xBCp, const float* __restrict__ dtv,
    const float* __restrict__ dAv, const float* __restrict__ Dp,
    const float4* __restrict__ Sbuf4, float* __restrict__ ydst /* = zxbcdt */) {
  int blk = blockIdx.x;                 // bh*NCHUNK + c
  int c  = blk & (NCHUNK - 1);
  int bh = blk >> 3;
  int b = bh >> 5, h = bh & 31;
  int tid = threadIdx.x;
  int wave = tid >> 6, lane = tid & 63;
  __shared__ __align__(16) float BCs[TB][2 * DSTATE];
  __shared__ __align__(16) float xs[TB][HEADDIM];
  __shared__ float dAs[TB], dts[TB];
  __shared__ float yred[4][TB][HEADDIM];
  float S[32];
  if (c > 0) {
    size_t base4 = (size_t)(bh * (NCHUNK - 1) + (c - 1)) * 2048;
    #pragma unroll
    for (int j = 0; j < 8; ++j) {
      float4 v = Sbuf4[base4 + (size_t)j * 256 + tid];
      S[4*j+0] = v.x; S[4*j+1] = v.y; S[4*j+2] = v.z; S[4*j+3] = v.w;
    }
  } else {
    #pragma unroll
    for (int i = 0; i < 32; i++) S[i] = 0.f;
  }
  float Dh = Dp[h];
  const float* rowbase = xBCp + ((size_t)(b * L_) + c * CHUNK) * CONVCH;
  const size_t dtbase = ((size_t)(b * L_) + (size_t)c * CHUNK) * NHEADS + h;
  int nb = wave * 32;

  for (int t0 = 0; t0 < CHUNK; t0 += TB) {
    __syncthreads();
    #pragma unroll
    for (int i = 0; i < 8; ++i) {
      int idx = i * 256 + tid;
      int tt = idx >> 8, col = idx & 255;
      BCs[tt][col] = rowbase[(size_t)(t0 + tt) * CONVCH + DINNER + col];
    }
    #pragma unroll
    for (int i = 0; i < 2; ++i) {
      int idx = i * 256 + tid;
      int tt = idx >> 6, p = idx & 63;
      xs[tt][p] = rowbase[(size_t)(t0 + tt) * CONVCH + h * HEADDIM + p];
    }
    if (tid < TB) dAs[tid] = dAv[dtbase + (size_t)(t0 + tid) * NHEADS];
    else if (tid < 2 * TB) dts[tid - TB] = dtv[dtbase + (size_t)(t0 + tid - TB) * NHEADS];
    __syncthreads();
    #pragma unroll
    for (int tt = 0; tt < TB; ++tt) {
      float dA = dAs[tt];
      float dtx = dts[tt] * xs[tt][lane];
      float yp0 = 0.f, yp1 = 0.f, yp2 = 0.f, yp3 = 0.f;
      #pragma unroll
      for (int j = 0; j < 8; ++j) {
        float4 bb = *(const float4*)&BCs[tt][nb + 4 * j];
        float4 cc = *(const float4*)&BCs[tt][DSTATE + nb + 4 * j];
        float h0 = fmaf(dA, S[4*j+0], dtx * bb.x); S[4*j+0] = h0; yp0 = fmaf(h0, cc.x, yp0);
        float h1 = fmaf(dA, S[4*j+1], dtx * bb.y); S[4*j+1] = h1; yp1 = fmaf(h1, cc.y, yp1);
        float h2 = fmaf(dA, S[4*j+2], dtx * bb.z); S[4*j+2] = h2; yp2 = fmaf(h2, cc.z, yp2);
        float h3 = fmaf(dA, S[4*j+3], dtx * bb.w); S[4*j+3] = h3; yp3 = fmaf(h3, cc.w, yp3);
      }
      yred[wave][tt][lane] = (yp0 + yp1) + (yp2 + yp3);
    }
    __syncthreads();
    #pragma unroll
    for (int i = 0; i < 2; ++i) {
      int idx = i * 256 + tid;
      int tt = idx >> 6, p = idx & 63;
      float s = (yred[0][tt][p] + yred[1][tt][p]) + (yred[2][tt][p] + yred[3][tt][p]);
      int t = c * CHUNK + t0 + tt;
      ydst[((size_t)(b * L_) + t) * DINPROJ + DINNER + h * HEADDIM + p] =
          fmaf(Dh, xs[tt][p], s);
    }
  }
}

// ---------------- gate with silu(z) + RMSNorm -> bf16 hi/lo planes [NTOK][2048] ----------------
__global__ __launch_bounds__(256) void gate_rms_split_kernel(
    const float* __restrict__ zxbcdt, const float* __restrict__ ssm_w,
    __bf16* __restrict__ hi, __bf16* __restrict__ lo) {
  int row = blockIdx.x;
  const float* yr = zxbcdt + (size_t)row * DINPROJ + DINNER;
  const float* zr = zxbcdt + (size_t)row * DINPROJ;
  int tid = threadIdx.x;
  float vals[8];
  float ssq = 0.f;
  #pragma unroll
  for (int q = 0; q < 2; ++q) {
    int col = q * 1024 + tid * 4;
    float4 yv = *(const float4*)&yr[col];
    float4 zv = *(const float4*)&zr[col];
    float g0 = yv.x * silu_f(zv.x);
    float g1 = yv.y * silu_f(zv.y);
    float g2 = yv.z * silu_f(zv.z);
    float g3 = yv.w * silu_f(zv.w);
    vals[q*4+0] = g0; vals[q*4+1] = g1; vals[q*4+2] = g2; vals[q*4+3] = g3;
    ssq += g0*g0 + g1*g1 + g2*g2 + g3*g3;
  }
  #pragma unroll
  for (int off = 32; off > 0; off >>= 1) ssq += __shfl_down(ssq, off);
  __shared__ float red[4];
  __shared__ float stot;
  int lane = tid & 63, wv = tid >> 6;
  if (lane == 0) red[wv] = ssq;
  __syncthreads();
  if (tid == 0) stot = red[0] + red[1] + red[2] + red[3];
  __syncthreads();
  float scale = rsqrtf(stot / (float)DINNER + 1e-5f);
  #pragma unroll
  for (int q = 0; q < 2; ++q) {
    int col = q * 1024 + tid * 4;
    float4 w4 = *(const float4*)&ssm_w[col];
    float o0 = vals[q*4+0] * scale * w4.x;
    float o1 = vals[q*4+1] * scale * w4.y;
    float o2 = vals[q*4+2] * scale * w4.z;
    float o3 = vals[q*4+3] * scale * w4.w;
    v4bf h, l;
    h[0] = (__bf16)o0; l[0] = (__bf16)(o0 - (float)h[0]);
    h[1] = (__bf16)o1; l[1] = (__bf16)(o1 - (float)h[1]);
    h[2] = (__bf16)o2; l[2] = (__bf16)(o2 - (float)h[2]);
    h[3] = (__bf16)o3; l[3] = (__bf16)(o3 - (float)h[3]);
    size_t ob = (size_t)row * DINNER + col;
    *(v4bf*)&hi[ob] = h;
    *(v4bf*)&lo[ob] = l;
  }
}

extern "C" void kernel_launch(void* const* d_in, const int* in_sizes, int n_in,
                              void* d_out, int out_size, void* d_ws, size_t ws_size,
                              hipStream_t stream) {
  const float* x          = (const float*)d_in[0];
  const float* norm_w     = (const float*)d_in[1];
  const float* in_proj_w  = (const float*)d_in[2];
  const float* conv_w     = (const float*)d_in[3];
  const float* conv_b     = (const float*)d_in[4];
  const float* dt_bias    = (const float*)d_in[5];
  const float* A_log      = (const float*)d_in[6];
  const float* Dp         = (const float*)d_in[7];
  const float* ssm_norm_w = (const float*)d_in[8];
  const float* out_proj_w = (const float*)d_in[9];
  float* out = (float*)d_out;

  // ---- workspace layout (phase-aliased), floats ----
  // P0 (persistent): sc | zxbcdt | dtb | dAb
  // P1 (union):  W1hi/lo bf16 (GEMM1) / Sbuf+Pbuf (scan) / W2hi/lo (GEMM2)
  // P2 (union):  A1hi/lo bf16 (GEMM1) / xBCp f32 (conv->scan) / A2hi/lo (GEMM2)
  const size_t P0f = (size_t)NTOK + (size_t)NTOK*DINPROJ + 2u*(size_t)NTOK*NHEADS;
  const size_t P1f = (size_t)SBLKS * 8192 + 1024;  // Sbuf + Pbuf(896, padded)
  const size_t P2f = (size_t)NTOK * CONVCH;
  const size_t needed = (P0f + P1f + P2f) * sizeof(float);
  if (ws_size < needed) {
    size_t n = (size_t)NTOK * DMODEL;
    copy_x_kernel<<<(int)((n + 255) / 256), 256, 0, stream>>>(x, out, n);
    return;
  }

  float* ws     = (float*)d_ws;
  float* sc     = ws;
  float* zxbcdt = sc + NTOK;
  float* dtb    = zxbcdt + (size_t)NTOK * DINPROJ;
  float* dAb    = dtb + (size_t)NTOK * NHEADS;
  float* P1     = dAb + (size_t)NTOK * NHEADS;
  float* P2     = P1 + P1f;

  // P1 overlays
  __bf16* W1hi = (__bf16*)P1;                               // 4384*1024
  __bf16* W1lo = W1hi + (size_t)DINPROJ * DMODEL;
  float*  Sbuf = P1;
  float*  Pbuf = Sbuf + (size_t)SBLKS * 8192;
  __bf16* W2hi = (__bf16*)P1;                               // 1024*2048
  __bf16* W2lo = W2hi + (size_t)DMODEL * DINNER;
  // P2 overlays
  __bf16* A1hi = (__bf16*)P2;                               // 8192*1024
  __bf16* A1lo = A1hi + (size_t)NTOK * DMODEL;
  float*  xBCp = P2;
  __bf16* A2hi = (__bf16*)P2;                               // 8192*2048
  __bf16* A2lo = A2hi + (size_t)NTOK * DINNER;

  // 1) rmsnorm scale
  rms_scale_kernel<<<NTOK, 256, 0, stream>>>(x, sc);
  // 2) split A1 = rmsnorm(x), W1 = in_proj_w
  split_a1_kernel<<<(int)((size_t)NTOK * DMODEL / 1024), 256, 0, stream>>>(
      x, sc, norm_w, A1hi, A1lo);
  split_kernel<<<(int)((size_t)DINPROJ * DMODEL / 1024), 256, 0, stream>>>(
      in_proj_w, W1hi, W1lo);
  // 3) GEMM1 (MFMA bf16x3): zxbcdt = A1 · W1^T
  gemm_mfma_kernel<<<dim3((DINPROJ + 127) / 128, NTOK / 128), 256, 0, stream>>>(
      A1hi, A1lo, W1hi, W1lo, zxbcdt, nullptr, NTOK, DINPROJ, DMODEL);
  // 4) conv + silu  (overwrites A1 region -- A1 is dead)
  conv_silu_kernel<<<(int)(((size_t)NTOK * CONVCH) / 256), 256, 0, stream>>>(
      zxbcdt, conv_w, conv_b, xBCp);
  // 5) dt/dA
  dt_prep_kernel<<<(NTOK * NHEADS) / 256, 256, 0, stream>>>(
      zxbcdt, dt_bias, A_log, dtb, dAb);
  // 6) chunked scan (Sbuf overwrites W1 region -- W1 is dead)
  chunk_state_kernel<<<SBLKS, 256, 0, stream>>>(xBCp, dtb, dAb, (float4*)Sbuf, Pbuf);
  combine_kernel<<<B_ * NHEADS, 256, 0, stream>>>((float4*)Sbuf, Pbuf);
  chunk_scan_kernel<<<B_ * NHEADS * NCHUNK, 256, 0, stream>>>(
      xBCp, dtb, dAb, Dp, (const float4*)Sbuf, zxbcdt);
  // 7) gate + rmsnorm -> A2 planes (overwrites xBCp -- dead)
  gate_rms_split_kernel<<<NTOK, 256, 0, stream>>>(zxbcdt, ssm_norm_w, A2hi, A2lo);
  // 8) split W2 (overwrites Sbuf -- dead)
  split_kernel<<<(int)((size_t)DMODEL * DINNER / 1024), 256, 0, stream>>>(
      out_proj_w, W2hi, W2lo);
  // 9) GEMM2 (MFMA bf16x3) + residual
  gemm_mfma_kernel<<<dim3(DMODEL / 128, NTOK / 128), 256, 0, stream>>>(
      A2hi, A2lo, W2hi, W2lo, out, x, NTOK, DMODEL, DINNER);
}

// Round 13
// 957.983 us; speedup vs baseline: 3.5100x; 1.1014x over previous
//
#include <hip/hip_runtime.h>
#include <hip/hip_bf16.h>
#include <math.h>

#define B_      4
#define L_      2048
#define DMODEL  1024
#define DINNER  2048
#define DSTATE  128
#define NHEADS  32
#define HEADDIM 64
#define DINPROJ 4384   // 2*DINNER + 2*DSTATE + NHEADS
#define CONVCH  2304   // DINNER + 2*DSTATE
#define NTOK    (B_*L_)

#define CHUNK   256
#define NCHUNK  (L_/CHUNK)        // 8
#define TB      8                 // time-steps per LDS stage
#define SBLKS   (B_*NHEADS*(NCHUNK-1))   // 896 stored chunk states

typedef __bf16 v8bf __attribute__((ext_vector_type(8)));
typedef __bf16 v4bf __attribute__((ext_vector_type(4)));
typedef float  v4f  __attribute__((ext_vector_type(4)));

__device__ __forceinline__ float silu_f(float v) {
  return v / (1.0f + __expf(-v));
}

// ---------------- diagnostic fallback ----------------
__global__ __launch_bounds__(256) void copy_x_kernel(const float* __restrict__ x,
                                                     float* __restrict__ out, size_t n) {
  size_t i = (size_t)blockIdx.x * 256 + threadIdx.x;
  if (i < n) out[i] = x[i];
}

// ---------------- fused RMSNorm + bf16 hi/lo split: A1 = rmsnorm(x)*norm_w ----------------
// One block per row; each thread owns 4 elements (registers), so x is read ONCE.
__global__ __launch_bounds__(256) void rms_split_a1_kernel(
    const float* __restrict__ x, const float* __restrict__ nw,
    __bf16* __restrict__ hi, __bf16* __restrict__ lo) {
  int row = blockIdx.x;
  int tid = threadIdx.x;
  const float* xr = x + (size_t)row * DMODEL;
  float4 v = *(const float4*)&xr[tid * 4];
  float ssq = v.x*v.x + v.y*v.y + v.z*v.z + v.w*v.w;
  #pragma unroll
  for (int off = 32; off > 0; off >>= 1) ssq += __shfl_down(ssq, off);
  __shared__ float red[4];
  __shared__ float stot;
  int lane = tid & 63, wv = tid >> 6;
  if (lane == 0) red[wv] = ssq;
  __syncthreads();
  if (tid == 0) stot = red[0] + red[1] + red[2] + red[3];
  __syncthreads();
  float s = rsqrtf(stot / (float)DMODEL + 1e-4f);
  float4 wv4 = *(const float4*)&nw[tid * 4];
  float a0 = v.x * s * wv4.x, a1 = v.y * s * wv4.y;
  float a2 = v.z * s * wv4.z, a3 = v.w * s * wv4.w;
  v4bf h, l;
  h[0] = (__bf16)a0; l[0] = (__bf16)(a0 - (float)h[0]);
  h[1] = (__bf16)a1; l[1] = (__bf16)(a1 - (float)h[1]);
  h[2] = (__bf16)a2; l[2] = (__bf16)(a2 - (float)h[2]);
  h[3] = (__bf16)a3; l[3] = (__bf16)(a3 - (float)h[3]);
  size_t base = (size_t)row * DMODEL + tid * 4;
  *(v4bf*)&hi[base] = h;
  *(v4bf*)&lo[base] = l;
}

// ---------------- bf16 hi/lo split: plain (weights) ----------------
__global__ __launch_bounds__(256) void split_kernel(
    const float* __restrict__ in, __bf16* __restrict__ hi, __bf16* __restrict__ lo) {
  size_t base = ((size_t)blockIdx.x * 256 + threadIdx.x) * 4;
  float4 xv = *(const float4*)&in[base];
  v4bf h, l;
  h[0] = (__bf16)xv.x; l[0] = (__bf16)(xv.x - (float)h[0]);
  h[1] = (__bf16)xv.y; l[1] = (__bf16)(xv.y - (float)h[1]);
  h[2] = (__bf16)xv.z; l[2] = (__bf16)(xv.z - (float)h[2]);
  h[3] = (__bf16)xv.w; l[3] = (__bf16)(xv.w - (float)h[3]);
  *(v4bf*)&hi[base] = h;
  *(v4bf*)&lo[base] = l;
}

// ---------------- bf16x3 MFMA GEMM: C[m,n] = A[m,:]·W[n,:] (+resid) ----------------
// 1D grid with XCD-aware bijective swizzle (nwg % 8 == 0 for all launches):
// hw-block i -> work (i&7)*(nwg/8) + (i>>3), so each XCD gets a CONTIGUOUS
// work chunk; n-fastest decomposition -> A-panel reused across consecutive
// blocks in the same XCD L2. Inner structure identical to round-12 kernel.
__global__ __launch_bounds__(256) void gemm_mfma_kernel(
    const __bf16* __restrict__ Ahi, const __bf16* __restrict__ Alo,
    const __bf16* __restrict__ Whi, const __bf16* __restrict__ Wlo,
    float* __restrict__ C, const float* __restrict__ resid,
    int M, int N, int K, int nbx) {
  __shared__ __align__(16) __bf16 Ah[128 * 40];
  __shared__ __align__(16) __bf16 Al[128 * 40];
  __shared__ __align__(16) __bf16 Bh[128 * 40];
  __shared__ __align__(16) __bf16 Bl[128 * 40];
  int tid = threadIdx.x;
  int nwg = gridDim.x;
  int id = blockIdx.x;
  int swz = (id & 7) * (nwg >> 3) + (id >> 3);   // bijective: nwg % 8 == 0
  int bx = swz % nbx;
  int by = swz / nbx;
  int bm = by * 128;
  int bn = bx * 128;
  int w = tid >> 6, lane = tid & 63;
  int wr = w >> 1, wc = w & 1;

  v4f acc[4][4];
  #pragma unroll
  for (int i = 0; i < 4; i++)
    #pragma unroll
    for (int j = 0; j < 4; j++) acc[i][j] = (v4f){0.f, 0.f, 0.f, 0.f};

  v8bf zz;
  #pragma unroll
  for (int z = 0; z < 8; z++) zz[z] = (__bf16)0.f;

  // staging coords (2 chunks of 16B per thread per tile)
  int r0 = tid >> 2,          c0 = tid & 3;
  int r1 = (tid + 256) >> 2,  c1 = (tid + 256) & 3;
  int arow = wr * 64 + (lane & 15);
  int brow = wc * 64 + (lane & 15);
  int koff = (lane >> 4) * 8;

  for (int k0 = 0; k0 < K; k0 += 32) {
    __syncthreads();
    {
      size_t ga0 = (size_t)(bm + r0) * K + k0 + c0 * 8;
      size_t ga1 = (size_t)(bm + r1) * K + k0 + c1 * 8;
      *(v8bf*)&Ah[r0 * 40 + c0 * 8] = *(const v8bf*)&Ahi[ga0];
      *(v8bf*)&Al[r0 * 40 + c0 * 8] = *(const v8bf*)&Alo[ga0];
      *(v8bf*)&Ah[r1 * 40 + c1 * 8] = *(const v8bf*)&Ahi[ga1];
      *(v8bf*)&Al[r1 * 40 + c1 * 8] = *(const v8bf*)&Alo[ga1];
      v8bf b0h = zz, b0l = zz, b1h = zz, b1l = zz;
      if (bn + r0 < N) {
        size_t gb = (size_t)(bn + r0) * K + k0 + c0 * 8;
        b0h = *(const v8bf*)&Whi[gb]; b0l = *(const v8bf*)&Wlo[gb];
      }
      if (bn + r1 < N) {
        size_t gb = (size_t)(bn + r1) * K + k0 + c1 * 8;
        b1h = *(const v8bf*)&Whi[gb]; b1l = *(const v8bf*)&Wlo[gb];
      }
      *(v8bf*)&Bh[r0 * 40 + c0 * 8] = b0h;
      *(v8bf*)&Bl[r0 * 40 + c0 * 8] = b0l;
      *(v8bf*)&Bh[r1 * 40 + c1 * 8] = b1h;
      *(v8bf*)&Bl[r1 * 40 + c1 * 8] = b1l;
    }
    __syncthreads();

    v8bf afh[4], afl[4], bfh[4], bfl[4];
    #pragma unroll
    for (int f = 0; f < 4; ++f) {
      afh[f] = *(const v8bf*)&Ah[(arow + f * 16) * 40 + koff];
      afl[f] = *(const v8bf*)&Al[(arow + f * 16) * 40 + koff];
      bfh[f] = *(const v8bf*)&Bh[(brow + f * 16) * 40 + koff];
      bfl[f] = *(const v8bf*)&Bl[(brow + f * 16) * 40 + koff];
    }
    #pragma unroll
    for (int i = 0; i < 4; ++i)
      #pragma unroll
      for (int j = 0; j < 4; ++j) {
        acc[i][j] = __builtin_amdgcn_mfma_f32_16x16x32_bf16(afh[i], bfh[j], acc[i][j], 0, 0, 0);
        acc[i][j] = __builtin_amdgcn_mfma_f32_16x16x32_bf16(afh[i], bfl[j], acc[i][j], 0, 0, 0);
        acc[i][j] = __builtin_amdgcn_mfma_f32_16x16x32_bf16(afl[i], bfh[j], acc[i][j], 0, 0, 0);
      }
  }

  // epilogue: C/D layout col=lane&15, row=(lane>>4)*4+e  [m89-verified]
  #pragma unroll
  for (int i = 0; i < 4; ++i) {
    int mb = bm + wr * 64 + i * 16 + (lane >> 4) * 4;
    #pragma unroll
    for (int j = 0; j < 4; ++j) {
      int n = bn + wc * 64 + j * 16 + (lane & 15);
      if (n < N) {
        #pragma unroll
        for (int e = 0; e < 4; ++e) {
          size_t off = (size_t)(mb + e) * N + n;
          float v = acc[i][j][e];
          if (resid) v += resid[off];
          C[off] = v;
        }
      }
    }
  }
}

// ---------------- causal depthwise conv (k=4) + bias + silu ----------------
__global__ __launch_bounds__(256) void conv_silu_kernel(
    const float* __restrict__ zxbcdt, const float* __restrict__ conv_w,
    const float* __restrict__ conv_b, float* __restrict__ xBCp) {
  size_t idx = (size_t)blockIdx.x * 256 + threadIdx.x;  // b*L*CONVCH
  int c = (int)(idx % CONVCH);
  int t = (int)((idx / CONVCH) % L_);
  int b = (int)(idx / ((size_t)CONVCH * L_));
  const float* src = zxbcdt + (size_t)(b * L_) * DINPROJ + DINNER + c;
  float w0 = conv_w[c*4+0], w1 = conv_w[c*4+1], w2 = conv_w[c*4+2], w3 = conv_w[c*4+3];
  float acc = conv_b[c];
  if (t >= 3) acc = fmaf(w0, src[(size_t)(t-3)*DINPROJ], acc);
  if (t >= 2) acc = fmaf(w1, src[(size_t)(t-2)*DINPROJ], acc);
  if (t >= 1) acc = fmaf(w2, src[(size_t)(t-1)*DINPROJ], acc);
  acc = fmaf(w3, src[(size_t)t*DINPROJ], acc);
  xBCp[idx] = silu_f(acc);
}

// ---------------- dt = softplus(dt_raw + bias); dA = exp(-exp(A_log)*dt) ----------------
__global__ __launch_bounds__(256) void dt_prep_kernel(
    const float* __restrict__ zxbcdt, const float* __restrict__ dt_bias,
    const float* __restrict__ A_log, float* __restrict__ dt_out,
    float* __restrict__ dA_out) {
  int idx = blockIdx.x * 256 + threadIdx.x;  // NTOK*NHEADS
  int hh = idx & (NHEADS - 1);
  int row = idx >> 5;
  float v = zxbcdt[(size_t)row * DINPROJ + (DINPROJ - NHEADS) + hh] + dt_bias[hh];
  float sp = (v > 0.f) ? (v + log1pf(expf(-v))) : log1pf(expf(v));
  dt_out[idx] = sp;
  dA_out[idx] = expf(-expf(A_log[hh]) * sp);
}

// ============ Chunked scan pass A: zero-init chunk states ============
__global__ __launch_bounds__(256) void chunk_state_kernel(
    const float* __restrict__ xBCp, const float* __restrict__ dtv,
    const float* __restrict__ dAv, float4* __restrict__ Sbuf4,
    float* __restrict__ Pbuf) {
  int blk = blockIdx.x;
  int c  = blk % (NCHUNK - 1);
  int bh = blk / (NCHUNK - 1);
  int b = bh >> 5, h = bh & 31;
  int tid = threadIdx.x;
  int wave = tid >> 6, lane = tid & 63;
  __shared__ __align__(16) float Bs[TB][DSTATE];
  __shared__ __align__(16) float xs[TB][HEADDIM];
  __shared__ float dAs[TB], dts[TB];
  float S[32];
  #pragma unroll
  for (int i = 0; i < 32; i++) S[i] = 0.f;
  float pdec = 1.f;
  const float* rowbase = xBCp + ((size_t)(b * L_) + c * CHUNK) * CONVCH;
  const size_t dtbase = ((size_t)(b * L_) + (size_t)c * CHUNK) * NHEADS + h;
  int nb = wave * 32;

  for (int t0 = 0; t0 < CHUNK; t0 += TB) {
    __syncthreads();
    #pragma unroll
    for (int i = 0; i < 4; ++i) {
      int idx = i * 256 + tid;
      int tt = idx >> 7, n = idx & 127;
      Bs[tt][n] = rowbase[(size_t)(t0 + tt) * CONVCH + DINNER + n];
    }
    #pragma unroll
    for (int i = 0; i < 2; ++i) {
      int idx = i * 256 + tid;
      int tt = idx >> 6, p = idx & 63;
      xs[tt][p] = rowbase[(size_t)(t0 + tt) * CONVCH + h * HEADDIM + p];
    }
    if (tid < TB) dAs[tid] = dAv[dtbase + (size_t)(t0 + tid) * NHEADS];
    else if (tid < 2 * TB) dts[tid - TB] = dtv[dtbase + (size_t)(t0 + tid - TB) * NHEADS];
    __syncthreads();
    #pragma unroll
    for (int tt = 0; tt < TB; ++tt) {
      float dA = dAs[tt];
      float dtx = dts[tt] * xs[tt][lane];
      pdec *= dA;
      #pragma unroll
      for (int j = 0; j < 8; ++j) {
        float4 bb = *(const float4*)&Bs[tt][nb + 4 * j];
        S[4*j+0] = fmaf(dA, S[4*j+0], dtx * bb.x);
        S[4*j+1] = fmaf(dA, S[4*j+1], dtx * bb.y);
        S[4*j+2] = fmaf(dA, S[4*j+2], dtx * bb.z);
        S[4*j+3] = fmaf(dA, S[4*j+3], dtx * bb.w);
      }
    }
  }
  size_t base4 = (size_t)blk * 2048;
  #pragma unroll
  for (int j = 0; j < 8; ++j)
    Sbuf4[base4 + (size_t)j * 256 + tid] = make_float4(S[4*j], S[4*j+1], S[4*j+2], S[4*j+3]);
  if (tid == 0) Pbuf[blk] = pdec;
}

// ============ Pass B: serial prefix over chunks ============
__global__ __launch_bounds__(256) void combine_kernel(float4* __restrict__ Sbuf4,
                                                      const float* __restrict__ Pbuf) {
  int bh = blockIdx.x;
  int tid = threadIdx.x;
  float4 run[8];
  #pragma unroll
  for (int j = 0; j < 8; ++j) run[j] = make_float4(0.f, 0.f, 0.f, 0.f);
  for (int c = 0; c < NCHUNK - 1; ++c) {
    size_t base4 = (size_t)(bh * (NCHUNK - 1) + c) * 2048;
    float P = Pbuf[bh * (NCHUNK - 1) + c];
    #pragma unroll
    for (int j = 0; j < 8; ++j) {
      float4 v = Sbuf4[base4 + (size_t)j * 256 + tid];
      float4 nr;
      nr.x = fmaf(P, run[j].x, v.x);
      nr.y = fmaf(P, run[j].y, v.y);
      nr.z = fmaf(P, run[j].z, v.z);
      nr.w = fmaf(P, run[j].w, v.w);
      Sbuf4[base4 + (size_t)j * 256 + tid] = nr;
      run[j] = nr;
    }
  }
}

// ============ Pass C: y-producing recurrence per chunk ============
__global__ __launch_bounds__(256) void chunk_scan_kernel(
    const float* __restrict__ xBCp, const float* __restrict__ dtv,
    const float* __restrict__ dAv, const float* __restrict__ Dp,
    const float4* __restrict__ Sbuf4, float* __restrict__ ydst /* = zxbcdt */) {
  int blk = blockIdx.x;                 // bh*NCHUNK + c
  int c  = blk & (NCHUNK - 1);
  int bh = blk >> 3;
  int b = bh >> 5, h = bh & 31;
  int tid = threadIdx.x;
  int wave = tid >> 6, lane = tid & 63;
  __shared__ __align__(16) float BCs[TB][2 * DSTATE];
  __shared__ __align__(16) float xs[TB][HEADDIM];
  __shared__ float dAs[TB], dts[TB];
  __shared__ float yred[4][TB][HEADDIM];
  float S[32];
  if (c > 0) {
    size_t base4 = (size_t)(bh * (NCHUNK - 1) + (c - 1)) * 2048;
    #pragma unroll
    for (int j = 0; j < 8; ++j) {
      float4 v = Sbuf4[base4 + (size_t)j * 256 + tid];
      S[4*j+0] = v.x; S[4*j+1] = v.y; S[4*j+2] = v.z; S[4*j+3] = v.w;
    }
  } else {
    #pragma unroll
    for (int i = 0; i < 32; i++) S[i] = 0.f;
  }
  float Dh = Dp[h];
  const float* rowbase = xBCp + ((size_t)(b * L_) + c * CHUNK) * CONVCH;
  const size_t dtbase = ((size_t)(b * L_) + (size_t)c * CHUNK) * NHEADS + h;
  int nb = wave * 32;

  for (int t0 = 0; t0 < CHUNK; t0 += TB) {
    __syncthreads();
    #pragma unroll
    for (int i = 0; i < 8; ++i) {
      int idx = i * 256 + tid;
      int tt = idx >> 8, col = idx & 255;
      BCs[tt][col] = rowbase[(size_t)(t0 + tt) * CONVCH + DINNER + col];
    }
    #pragma unroll
    for (int i = 0; i < 2; ++i) {
      int idx = i * 256 + tid;
      int tt = idx >> 6, p = idx & 63;
      xs[tt][p] = rowbase[(size_t)(t0 + tt) * CONVCH + h * HEADDIM + p];
    }
    if (tid < TB) dAs[tid] = dAv[dtbase + (size_t)(t0 + tid) * NHEADS];
    else if (tid < 2 * TB) dts[tid - TB] = dtv[dtbase + (size_t)(t0 + tid - TB) * NHEADS];
    __syncthreads();
    #pragma unroll
    for (int tt = 0; tt < TB; ++tt) {
      float dA = dAs[tt];
      float dtx = dts[tt] * xs[tt][lane];
      float yp0 = 0.f, yp1 = 0.f, yp2 = 0.f, yp3 = 0.f;
      #pragma unroll
      for (int j = 0; j < 8; ++j) {
        float4 bb = *(const float4*)&BCs[tt][nb + 4 * j];
        float4 cc = *(const float4*)&BCs[tt][DSTATE + nb + 4 * j];
        float h0 = fmaf(dA, S[4*j+0], dtx * bb.x); S[4*j+0] = h0; yp0 = fmaf(h0, cc.x, yp0);
        float h1 = fmaf(dA, S[4*j+1], dtx * bb.y); S[4*j+1] = h1; yp1 = fmaf(h1, cc.y, yp1);
        float h2 = fmaf(dA, S[4*j+2], dtx * bb.z); S[4*j+2] = h2; yp2 = fmaf(h2, cc.z, yp2);
        float h3 = fmaf(dA, S[4*j+3], dtx * bb.w); S[4*j+3] = h3; yp3 = fmaf(h3, cc.w, yp3);
      }
      yred[wave][tt][lane] = (yp0 + yp1) + (yp2 + yp3);
    }
    __syncthreads();
    #pragma unroll
    for (int i = 0; i < 2; ++i) {
      int idx = i * 256 + tid;
      int tt = idx >> 6, p = idx & 63;
      float s = (yred[0][tt][p] + yred[1][tt][p]) + (yred[2][tt][p] + yred[3][tt][p]);
      int t = c * CHUNK + t0 + tt;
      ydst[((size_t)(b * L_) + t) * DINPROJ + DINNER + h * HEADDIM + p] =
          fmaf(Dh, xs[tt][p], s);
    }
  }
}

// ---------------- gate with silu(z) + RMSNorm -> bf16 hi/lo planes [NTOK][2048] ----------------
__global__ __launch_bounds__(256) void gate_rms_split_kernel(
    const float* __restrict__ zxbcdt, const float* __restrict__ ssm_w,
    __bf16* __restrict__ hi, __bf16* __restrict__ lo) {
  int row = blockIdx.x;
  const float* yr = zxbcdt + (size_t)row * DINPROJ + DINNER;
  const float* zr = zxbcdt + (size_t)row * DINPROJ;
  int tid = threadIdx.x;
  float vals[8];
  float ssq = 0.f;
  #pragma unroll
  for (int q = 0; q < 2; ++q) {
    int col = q * 1024 + tid * 4;
    float4 yv = *(const float4*)&yr[col];
    float4 zv = *(const float4*)&zr[col];
    float g0 = yv.x * silu_f(zv.x);
    float g1 = yv.y * silu_f(zv.y);
    float g2 = yv.z * silu_f(zv.z);
    float g3 = yv.w * silu_f(zv.w);
    vals[q*4+0] = g0; vals[q*4+1] = g1; vals[q*4+2] = g2; vals[q*4+3] = g3;
    ssq += g0*g0 + g1*g1 + g2*g2 + g3*g3;
  }
  #pragma unroll
  for (int off = 32; off > 0; off >>= 1) ssq += __shfl_down(ssq, off);
  __shared__ float red[4];
  __shared__ float stot;
  int lane = tid & 63, wv = tid >> 6;
  if (lane == 0) red[wv] = ssq;
  __syncthreads();
  if (tid == 0) stot = red[0] + red[1] + red[2] + red[3];
  __syncthreads();
  float scale = rsqrtf(stot / (float)DINNER + 1e-5f);
  #pragma unroll
  for (int q = 0; q < 2; ++q) {
    int col = q * 1024 + tid * 4;
    float4 w4 = *(const float4*)&ssm_w[col];
    float o0 = vals[q*4+0] * scale * w4.x;
    float o1 = vals[q*4+1] * scale * w4.y;
    float o2 = vals[q*4+2] * scale * w4.z;
    float o3 = vals[q*4+3] * scale * w4.w;
    v4bf h, l;
    h[0] = (__bf16)o0; l[0] = (__bf16)(o0 - (float)h[0]);
    h[1] = (__bf16)o1; l[1] = (__bf16)(o1 - (float)h[1]);
    h[2] = (__bf16)o2; l[2] = (__bf16)(o2 - (float)h[2]);
    h[3] = (__bf16)o3; l[3] = (__bf16)(o3 - (float)h[3]);
    size_t ob = (size_t)row * DINNER + col;
    *(v4bf*)&hi[ob] = h;
    *(v4bf*)&lo[ob] = l;
  }
}

extern "C" void kernel_launch(void* const* d_in, const int* in_sizes, int n_in,
                              void* d_out, int out_size, void* d_ws, size_t ws_size,
                              hipStream_t stream) {
  const float* x          = (const float*)d_in[0];
  const float* norm_w     = (const float*)d_in[1];
  const float* in_proj_w  = (const float*)d_in[2];
  const float* conv_w     = (const float*)d_in[3];
  const float* conv_b     = (const float*)d_in[4];
  const float* dt_bias    = (const float*)d_in[5];
  const float* A_log      = (const float*)d_in[6];
  const float* Dp         = (const float*)d_in[7];
  const float* ssm_norm_w = (const float*)d_in[8];
  const float* out_proj_w = (const float*)d_in[9];
  float* out = (float*)d_out;

  // ---- workspace layout (phase-aliased), floats ----
  // P0 (persistent): sc(unused pad) | zxbcdt | dtb | dAb
  // P1 (union):  W1hi/lo bf16 (GEMM1) / Sbuf+Pbuf (scan) / W2hi/lo (GEMM2)
  // P2 (union):  A1hi/lo bf16 (GEMM1) / xBCp f32 (conv->scan) / A2hi/lo (GEMM2)
  const size_t P0f = (size_t)NTOK + (size_t)NTOK*DINPROJ + 2u*(size_t)NTOK*NHEADS;
  const size_t P1f = (size_t)SBLKS * 8192 + 1024;  // Sbuf + Pbuf(896, padded)
  const size_t P2f = (size_t)NTOK * CONVCH;
  const size_t needed = (P0f + P1f + P2f) * sizeof(float);
  if (ws_size < needed) {
    size_t n = (size_t)NTOK * DMODEL;
    copy_x_kernel<<<(int)((n + 255) / 256), 256, 0, stream>>>(x, out, n);
    return;
  }

  float* ws     = (float*)d_ws;
  float* zxbcdt = ws + NTOK;                       // keep round-12 offsets
  float* dtb    = zxbcdt + (size_t)NTOK * DINPROJ;
  float* dAb    = dtb + (size_t)NTOK * NHEADS;
  float* P1     = dAb + (size_t)NTOK * NHEADS;
  float* P2     = P1 + P1f;

  // P1 overlays
  __bf16* W1hi = (__bf16*)P1;                               // 4384*1024
  __bf16* W1lo = W1hi + (size_t)DINPROJ * DMODEL;
  float*  Sbuf = P1;
  float*  Pbuf = Sbuf + (size_t)SBLKS * 8192;
  __bf16* W2hi = (__bf16*)P1;                               // 1024*2048
  __bf16* W2lo = W2hi + (size_t)DMODEL * DINNER;
  // P2 overlays
  __bf16* A1hi = (__bf16*)P2;                               // 8192*1024
  __bf16* A1lo = A1hi + (size_t)NTOK * DMODEL;
  float*  xBCp = P2;
  __bf16* A2hi = (__bf16*)P2;                               // 8192*2048
  __bf16* A2lo = A2hi + (size_t)NTOK * DINNER;

  // 1) fused rmsnorm + split A1; split W1
  rms_split_a1_kernel<<<NTOK, 256, 0, stream>>>(x, norm_w, A1hi, A1lo);
  split_kernel<<<(int)((size_t)DINPROJ * DMODEL / 1024), 256, 0, stream>>>(
      in_proj_w, W1hi, W1lo);
  // 2) GEMM1 (MFMA bf16x3, XCD-swizzled): zxbcdt = A1 · W1^T
  {
    int nbx = (DINPROJ + 127) / 128;               // 35
    int nwg = nbx * (NTOK / 128);                  // 2240, % 8 == 0
    gemm_mfma_kernel<<<nwg, 256, 0, stream>>>(
        A1hi, A1lo, W1hi, W1lo, zxbcdt, nullptr, NTOK, DINPROJ, DMODEL, nbx);
  }
  // 3) conv + silu  (overwrites A1 region -- A1 is dead)
  conv_silu_kernel<<<(int)(((size_t)NTOK * CONVCH) / 256), 256, 0, stream>>>(
      zxbcdt, conv_w, conv_b, xBCp);
  // 4) dt/dA
  dt_prep_kernel<<<(NTOK * NHEADS) / 256, 256, 0, stream>>>(
      zxbcdt, dt_bias, A_log, dtb, dAb);
  // 5) chunked scan (Sbuf overwrites W1 region -- W1 is dead)
  chunk_state_kernel<<<SBLKS, 256, 0, stream>>>(xBCp, dtb, dAb, (float4*)Sbuf, Pbuf);
  combine_kernel<<<B_ * NHEADS, 256, 0, stream>>>((float4*)Sbuf, Pbuf);
  chunk_scan_kernel<<<B_ * NHEADS * NCHUNK, 256, 0, stream>>>(
      xBCp, dtb, dAb, Dp, (const float4*)Sbuf, zxbcdt);
  // 6) gate + rmsnorm -> A2 planes (overwrites xBCp -- dead)
  gate_rms_split_kernel<<<NTOK, 256, 0, stream>>>(zxbcdt, ssm_norm_w, A2hi, A2lo);
  // 7) split W2 (overwrites Sbuf -- dead)
  split_kernel<<<(int)((size_t)DMODEL * DINNER / 1024), 256, 0, stream>>>(
      out_proj_w, W2hi, W2lo);
  // 8) GEMM2 (MFMA bf16x3, XCD-swizzled) + residual
  {
    int nbx = DMODEL / 128;                        // 8
    int nwg = nbx * (NTOK / 128);                  // 512, % 8 == 0
    gemm_mfma_kernel<<<nwg, 256, 0, stream>>>(
        A2hi, A2lo, W2hi, W2lo, out, x, NTOK, DMODEL, DINNER, nbx);
  }
}